// Round 1
// baseline (2235.384 us; speedup 1.0000x reference)
//
#include <hip/hip_runtime.h>

#define N_NODE 2048
#define D_DIM 64
#define ND ((size_t)(N_NODE) * (size_t)(D_DIM))   // 131072 floats per (b,l) frame
#define L_SEQ 12

__device__ __forceinline__ float relu_f(float x) { return fmaxf(x, 0.f); }

// ---------------------------------------------------------------------------
// K1: Gsum = mask ⊙ (G + G @ (G ⊙ mask)),  mask = 1 - I.   2048x2048x2048 f32.
// 64x64x64 tiles, 256 threads, 4x4 per thread.
// ---------------------------------------------------------------------------
__global__ __launch_bounds__(256) void k_graph_build(const float* __restrict__ G,
                                                     float* __restrict__ Gsum) {
    __shared__ float Ast[64][68];   // A^T tile: Ast[k][r]
    __shared__ float Bs[64][68];    // B tile:   Bs[k][c]
    const int tid = threadIdx.x;
    const int n0 = blockIdx.x * 64;
    const int m0 = blockIdx.y * 64;
    const int lrow = tid >> 4;
    const int lc4 = (tid & 15) * 4;
    const int r0 = (tid >> 4) * 4;
    const int c0 = (tid & 15) * 4;
    float acc[4][4] = {};
    for (int k0 = 0; k0 < N_NODE; k0 += 64) {
        #pragma unroll
        for (int p = 0; p < 4; ++p) {
            const int r = lrow + p * 16;
            const float4 v = *(const float4*)(G + (size_t)(n0 + r) * N_NODE + k0 + lc4);
            Ast[lc4 + 0][r] = v.x;
            Ast[lc4 + 1][r] = v.y;
            Ast[lc4 + 2][r] = v.z;
            Ast[lc4 + 3][r] = v.w;
        }
        #pragma unroll
        for (int p = 0; p < 4; ++p) {
            const int r = lrow + p * 16;
            float4 v = *(const float4*)(G + (size_t)(k0 + r) * N_NODE + m0 + lc4);
            const int dj = (k0 + r) - (m0 + lc4);   // zero g1 diagonal on load
            if (dj >= 0 && dj < 4) ((float*)&v)[dj] = 0.f;
            *(float4*)&Bs[r][lc4] = v;
        }
        __syncthreads();
        #pragma unroll 8
        for (int k = 0; k < 64; ++k) {
            const float4 a4 = *(const float4*)&Ast[k][r0];
            const float4 b4 = *(const float4*)&Bs[k][c0];
            const float a_[4] = {a4.x, a4.y, a4.z, a4.w};
            const float b_[4] = {b4.x, b4.y, b4.z, b4.w};
            #pragma unroll
            for (int i = 0; i < 4; ++i)
                #pragma unroll
                for (int j = 0; j < 4; ++j)
                    acc[i][j] = fmaf(a_[i], b_[j], acc[i][j]);
        }
        __syncthreads();
    }
    #pragma unroll
    for (int i = 0; i < 4; ++i) {
        const int n = n0 + r0 + i;
        const float4 g = *(const float4*)(G + (size_t)n * N_NODE + m0 + c0);
        float4 o;
        o.x = acc[i][0] + g.x;
        o.y = acc[i][1] + g.y;
        o.z = acc[i][2] + g.z;
        o.w = acc[i][3] + g.w;
        const int dj = n - (m0 + c0);              // final mask: zero diagonal
        if (dj >= 0 && dj < 4) ((float*)&o)[dj] = 0.f;
        *(float4*)(Gsum + (size_t)n * N_NODE + m0 + c0) = o;
    }
}

// ---------------------------------------------------------------------------
// K2: FC stage.  Xs[bt,n,d] = sum_kt relu( xw @ W_fc )[kt*64+d]
// xw(192) = concat(frame0[n,:], frame1[n,:], frame2[n,:]).
// A-tiles are the frames themselves (per K-chunk), B = W_fc rows. BM=64, BN=192.
// ---------------------------------------------------------------------------
__global__ __launch_bounds__(256) void k_fc(const float* __restrict__ f0,
                                            const float* __restrict__ f1,
                                            const float* __restrict__ f2,
                                            const float* __restrict__ W_fc,
                                            float* __restrict__ Xs_out,
                                            int t_count) {
    __shared__ float Ast[64][64];    // frame tile transposed: Ast[k][r]
    __shared__ float Bs[64][192];    // W_fc rows (k-chunk) x 192 cols
    const int tid = threadIdx.x;
    const int n0 = blockIdx.x * 64;
    const int bt = blockIdx.y;
    const int b = bt / t_count;
    const int t = bt % t_count;
    const size_t fr = (size_t)b * L_SEQ * ND + (size_t)t * ND + (size_t)n0 * D_DIM;
    const float* frames[3] = {f0 + fr, f1 + fr, f2 + fr};
    const int lrow = tid >> 4;
    const int lc4 = (tid & 15) * 4;
    const int r0 = (tid >> 4) * 4;
    const int c0 = (tid & 15) * 4;
    float acc[3][4][4] = {};
    #pragma unroll
    for (int kk = 0; kk < 3; ++kk) {
        const float* F = frames[kk];
        #pragma unroll
        for (int p = 0; p < 4; ++p) {
            const int r = lrow + p * 16;
            const float4 v = *(const float4*)(F + (size_t)r * D_DIM + lc4);
            Ast[lc4 + 0][r] = v.x;
            Ast[lc4 + 1][r] = v.y;
            Ast[lc4 + 2][r] = v.z;
            Ast[lc4 + 3][r] = v.w;
        }
        #pragma unroll
        for (int p = 0; p < 12; ++p) {
            const int f4i = tid + p * 256;          // 0..3071 float4s
            const int row = f4i / 48;
            const int c4 = (f4i % 48) * 4;
            *(float4*)&Bs[row][c4] =
                *(const float4*)(W_fc + (size_t)(kk * 64 + row) * 192 + c4);
        }
        __syncthreads();
        #pragma unroll 4
        for (int k = 0; k < 64; ++k) {
            const float4 a4 = *(const float4*)&Ast[k][r0];
            const float a_[4] = {a4.x, a4.y, a4.z, a4.w};
            #pragma unroll
            for (int jc = 0; jc < 3; ++jc) {
                const float4 w4 = *(const float4*)&Bs[k][jc * 64 + c0];
                const float w_[4] = {w4.x, w4.y, w4.z, w4.w};
                #pragma unroll
                for (int i = 0; i < 4; ++i)
                    #pragma unroll
                    for (int j = 0; j < 4; ++j)
                        acc[jc][i][j] = fmaf(a_[i], w_[j], acc[jc][i][j]);
            }
        }
        __syncthreads();
    }
    #pragma unroll
    for (int i = 0; i < 4; ++i) {
        float4 o;
        o.x = relu_f(acc[0][i][0]) + relu_f(acc[1][i][0]) + relu_f(acc[2][i][0]);
        o.y = relu_f(acc[0][i][1]) + relu_f(acc[1][i][1]) + relu_f(acc[2][i][1]);
        o.z = relu_f(acc[0][i][2]) + relu_f(acc[1][i][2]) + relu_f(acc[2][i][2]);
        o.w = relu_f(acc[0][i][3]) + relu_f(acc[1][i][3]) + relu_f(acc[2][i][3]);
        *(float4*)(Xs_out + ((size_t)bt * N_NODE + n0 + r0 + i) * D_DIM + c0) = o;
    }
}

// ---------------------------------------------------------------------------
// K3: out[bt,n,:] = ( Xs[bt,n,:]/3 + sum_m Gsum[n,m]*Xs[bt,m,:] ) @ W_gcn + b_gcn
// (X0 == Xs/3). GCN fused via LDS-staged C tile. Optionally mirrors the t==last
// tile into P frame 0 (stage B).
// ---------------------------------------------------------------------------
__global__ __launch_bounds__(256) void k_propagate(const float* __restrict__ Gsum,
                                                   const float* __restrict__ Xs,
                                                   const float* __restrict__ W_gcn,
                                                   const float* __restrict__ b_gcn,
                                                   float* __restrict__ out_base,
                                                   long long out_bt_stride,
                                                   float* __restrict__ p0_base,
                                                   int t_count) {
    __shared__ float Ast[64][68];   // Gsum tile transposed; reused as C^T tile
    __shared__ float Bs[64][68];    // Xs tile
    __shared__ float Ws[64][68];    // W_gcn
    const int tid = threadIdx.x;
    const int n0 = blockIdx.x * 64;
    const int bt = blockIdx.y;
    const float* Bp = Xs + (size_t)bt * ND;
    float* out = out_base + (size_t)bt * (size_t)out_bt_stride;
    const int lrow = tid >> 4;
    const int lc4 = (tid & 15) * 4;
    const int r0 = (tid >> 4) * 4;
    const int c0 = (tid & 15) * 4;
    #pragma unroll
    for (int p = 0; p < 4; ++p) {
        const int f4i = tid + p * 256;   // 1024 float4s of W_gcn
        const int row = f4i >> 4;
        const int c4 = (f4i & 15) * 4;
        *(float4*)&Ws[row][c4] = *(const float4*)(W_gcn + (size_t)row * D_DIM + c4);
    }
    float acc[4][4] = {};
    for (int k0 = 0; k0 < N_NODE; k0 += 64) {
        #pragma unroll
        for (int p = 0; p < 4; ++p) {
            const int r = lrow + p * 16;
            const float4 v = *(const float4*)(Gsum + (size_t)(n0 + r) * N_NODE + k0 + lc4);
            Ast[lc4 + 0][r] = v.x;
            Ast[lc4 + 1][r] = v.y;
            Ast[lc4 + 2][r] = v.z;
            Ast[lc4 + 3][r] = v.w;
        }
        #pragma unroll
        for (int p = 0; p < 4; ++p) {
            const int r = lrow + p * 16;
            *(float4*)&Bs[r][lc4] = *(const float4*)(Bp + (size_t)(k0 + r) * D_DIM + lc4);
        }
        __syncthreads();
        #pragma unroll 8
        for (int k = 0; k < 64; ++k) {
            const float4 a4 = *(const float4*)&Ast[k][r0];
            const float4 b4 = *(const float4*)&Bs[k][c0];
            const float a_[4] = {a4.x, a4.y, a4.z, a4.w};
            const float b_[4] = {b4.x, b4.y, b4.z, b4.w};
            #pragma unroll
            for (int i = 0; i < 4; ++i)
                #pragma unroll
                for (int j = 0; j < 4; ++j)
                    acc[i][j] = fmaf(a_[i], b_[j], acc[i][j]);
        }
        __syncthreads();
    }
    // C tile (acc + Xs/3) staged transposed into Ast for the fused GCN matmul
    #pragma unroll
    for (int i = 0; i < 4; ++i) {
        const float4 x = *(const float4*)(Bp + (size_t)(n0 + r0 + i) * D_DIM + c0);
        Ast[c0 + 0][r0 + i] = acc[i][0] + x.x * (1.f / 3.f);
        Ast[c0 + 1][r0 + i] = acc[i][1] + x.y * (1.f / 3.f);
        Ast[c0 + 2][r0 + i] = acc[i][2] + x.z * (1.f / 3.f);
        Ast[c0 + 3][r0 + i] = acc[i][3] + x.w * (1.f / 3.f);
    }
    __syncthreads();
    const float4 bb = *(const float4*)(b_gcn + c0);
    float acc2[4][4];
    #pragma unroll
    for (int i = 0; i < 4; ++i) {
        acc2[i][0] = bb.x; acc2[i][1] = bb.y; acc2[i][2] = bb.z; acc2[i][3] = bb.w;
    }
    #pragma unroll 8
    for (int d = 0; d < 64; ++d) {
        const float4 a4 = *(const float4*)&Ast[d][r0];
        const float4 w4 = *(const float4*)&Ws[d][c0];
        const float a_[4] = {a4.x, a4.y, a4.z, a4.w};
        const float w_[4] = {w4.x, w4.y, w4.z, w4.w};
        #pragma unroll
        for (int i = 0; i < 4; ++i)
            #pragma unroll
            for (int j = 0; j < 4; ++j)
                acc2[i][j] = fmaf(a_[i], w_[j], acc2[i][j]);
    }
    float* p0 = nullptr;
    if (p0_base != nullptr && (bt % t_count) == (t_count - 1))
        p0 = p0_base + (size_t)(bt / t_count) * L_SEQ * ND;
    #pragma unroll
    for (int i = 0; i < 4; ++i) {
        float4 o;
        o.x = acc2[i][0]; o.y = acc2[i][1]; o.z = acc2[i][2]; o.w = acc2[i][3];
        const size_t off = (size_t)(n0 + r0 + i) * D_DIM + c0;
        *(float4*)(out + off) = o;
        if (p0) *(float4*)(p0 + off) = o;
    }
}

// ---------------------------------------------------------------------------
// K4: forecast = P @ W_fore + b_fore.  rows = 4*12*2048, 64 -> 256.
// W_fore read through L1/L2 (64 KB, fully cache-resident).
// ---------------------------------------------------------------------------
__global__ __launch_bounds__(256) void k_forecast(const float* __restrict__ P,
                                                  const float* __restrict__ W_fore,
                                                  const float* __restrict__ b_fore,
                                                  float* __restrict__ out) {
    __shared__ float Ast[64][64];
    const int tid = threadIdx.x;
    const size_t row0 = (size_t)blockIdx.x * 64;
    const int lrow = tid >> 4;
    const int lc4 = (tid & 15) * 4;
    const int r0 = (tid >> 4) * 4;
    const int c0 = (tid & 15) * 4;
    #pragma unroll
    for (int p = 0; p < 4; ++p) {
        const int r = lrow + p * 16;
        const float4 v = *(const float4*)(P + (row0 + r) * D_DIM + lc4);
        Ast[lc4 + 0][r] = v.x;
        Ast[lc4 + 1][r] = v.y;
        Ast[lc4 + 2][r] = v.z;
        Ast[lc4 + 3][r] = v.w;
    }
    __syncthreads();
    float acc[4][4][4];
    #pragma unroll
    for (int jc = 0; jc < 4; ++jc) {
        const float4 bb = *(const float4*)(b_fore + jc * 64 + c0);
        #pragma unroll
        for (int i = 0; i < 4; ++i) {
            acc[jc][i][0] = bb.x; acc[jc][i][1] = bb.y;
            acc[jc][i][2] = bb.z; acc[jc][i][3] = bb.w;
        }
    }
    #pragma unroll 4
    for (int k = 0; k < 64; ++k) {
        const float4 a4 = *(const float4*)&Ast[k][r0];
        const float a_[4] = {a4.x, a4.y, a4.z, a4.w};
        #pragma unroll
        for (int jc = 0; jc < 4; ++jc) {
            const float4 w4 = *(const float4*)(W_fore + (size_t)k * 256 + jc * 64 + c0);
            const float w_[4] = {w4.x, w4.y, w4.z, w4.w};
            #pragma unroll
            for (int i = 0; i < 4; ++i)
                #pragma unroll
                for (int j = 0; j < 4; ++j)
                    acc[jc][i][j] = fmaf(a_[i], w_[j], acc[jc][i][j]);
        }
    }
    #pragma unroll
    for (int i = 0; i < 4; ++i)
        #pragma unroll
        for (int jc = 0; jc < 4; ++jc) {
            float4 o;
            o.x = acc[jc][i][0]; o.y = acc[jc][i][1];
            o.z = acc[jc][i][2]; o.w = acc[jc][i][3];
            *(float4*)(out + (row0 + r0 + i) * 256 + jc * 64 + c0) = o;
        }
}

// ---------------------------------------------------------------------------
// K5: back = relu(Z @ W_back + b_back); u = X[:,2:12] - back; layernorm(u).
// One wave (64 lanes == D) per row; shfl broadcast for the 64x64 dot.
// ---------------------------------------------------------------------------
__global__ __launch_bounds__(256) void k_backcast(const float* __restrict__ Z,
                                                  const float* __restrict__ X,
                                                  const float* __restrict__ W_back,
                                                  const float* __restrict__ b_back,
                                                  const float* __restrict__ gamma,
                                                  const float* __restrict__ beta,
                                                  float* __restrict__ out) {
    const int tid = threadIdx.x;
    const int lane = tid & 63;
    const int wid = tid >> 6;
    const size_t row = (size_t)blockIdx.x * 4 + wid;   // (b*10+t)*2048 + n
    const int bt = (int)(row >> 11);
    const int b = bt / 10;
    const int t = bt % 10;
    const size_t n = row & 2047;
    const float z = Z[row * D_DIM + lane];
    float back = b_back[lane];
    #pragma unroll 8
    for (int k = 0; k < 64; ++k) {
        const float zk = __shfl(z, k, 64);
        back = fmaf(zk, W_back[k * D_DIM + lane], back);
    }
    const float xr = X[(((size_t)b * L_SEQ + t + 2) * N_NODE + n) * D_DIM + lane];
    const float u = xr - fmaxf(back, 0.f);
    float s = u;
    #pragma unroll
    for (int off = 32; off > 0; off >>= 1) s += __shfl_xor(s, off, 64);
    const float mu = s * (1.f / 64.f);
    const float dv = u - mu;
    float s2 = dv * dv;
    #pragma unroll
    for (int off = 32; off > 0; off >>= 1) s2 += __shfl_xor(s2, off, 64);
    const float var = s2 * (1.f / 64.f);
    out[row * D_DIM + lane] = dv * rsqrtf(var + 1e-5f) * gamma[lane] + beta[lane];
}

// ---------------------------------------------------------------------------
extern "C" void kernel_launch(void* const* d_in, const int* in_sizes, int n_in,
                              void* d_out, int out_size, void* d_ws, size_t ws_size,
                              hipStream_t stream) {
    (void)in_sizes; (void)n_in; (void)out_size; (void)ws_size;
    const float* X      = (const float*)d_in[0];   // (4,12,2048,64)
    const float* X_spa  = (const float*)d_in[1];   // (4,12,2048,64)
    const float* G      = (const float*)d_in[2];   // (2048,2048)
    const float* W_fc   = (const float*)d_in[3];   // (192,192)
    const float* W_gcn  = (const float*)d_in[4];   // (64,64)
    const float* b_gcn  = (const float*)d_in[5];   // (64)
    const float* W_fore = (const float*)d_in[6];   // (64,256)
    const float* b_fore = (const float*)d_in[7];   // (256)
    const float* W_back = (const float*)d_in[8];   // (64,64)
    const float* b_back = (const float*)d_in[9];   // (64)
    const float* gamma  = (const float*)d_in[10];  // (64)
    const float* beta   = (const float*)d_in[11];  // (64)

    float* backcast = (float*)d_out;                         // 4*10*2048*64
    float* forecast = (float*)d_out + (size_t)5242880;       // 4*12*2048*256

    // workspace layout (floats): all regions fully written before read
    float* wsf  = (float*)d_ws;
    float* Gsum = wsf;                                   // 2048*2048      = 4,194,304
    float* Xs   = Gsum + (size_t)N_NODE * N_NODE;        // 40*ND          = 5,242,880
    float* Z    = Xs + (size_t)40 * ND;                  // 40*ND          = 5,242,880
    float* P    = Z + (size_t)40 * ND;                   // 4*12*ND        = 6,291,456
                                                         // total ≈ 84 MB

    const dim3 blk(256);

    // Gsum = mask*(G + G@(G*mask))
    k_graph_build<<<dim3(32, 32), blk, 0, stream>>>(G, Gsum);

    // Stage B: Z over t=0..9 (40 bt batches); also writes P frame 0 (= Z[:,9])
    k_fc<<<dim3(32, 40), blk, 0, stream>>>(X_spa, X_spa + ND, X_spa + 2 * ND,
                                           W_fc, Xs, 10);
    k_propagate<<<dim3(32, 40), blk, 0, stream>>>(Gsum, Xs, W_gcn, b_gcn,
                                                  Z, (long long)ND, P, 10);

    // Stage C: 11 serial autoregressive steps, each t=1 (4 bt batches)
    for (int i = 1; i <= 11; ++i) {
        const float *f0, *f1, *f2;
        if (i == 1)      { f0 = X_spa + 10 * ND; f1 = X_spa + 11 * ND; f2 = P; }
        else if (i == 2) { f0 = X_spa + 11 * ND; f1 = P;               f2 = P + ND; }
        else             { f0 = P + (size_t)(i - 3) * ND;
                           f1 = P + (size_t)(i - 2) * ND;
                           f2 = P + (size_t)(i - 1) * ND; }
        k_fc<<<dim3(32, 4), blk, 0, stream>>>(f0, f1, f2, W_fc, Xs, 1);
        k_propagate<<<dim3(32, 4), blk, 0, stream>>>(Gsum, Xs, W_gcn, b_gcn,
                                                     P + (size_t)i * ND,
                                                     (long long)(L_SEQ * ND),
                                                     nullptr, 1);
    }

    // forecast = P @ W_fore + b_fore
    k_forecast<<<dim3(1536), blk, 0, stream>>>(P, W_fore, b_fore, forecast);

    // backcast = LN(X[:,2:] - relu(Z @ W_back + b_back))
    k_backcast<<<dim3(20480), blk, 0, stream>>>(Z, X, W_back, b_back,
                                                gamma, beta, backcast);
}

// Round 2
// 1216.464 us; speedup vs baseline: 1.8376x; 1.8376x over previous
//
#include <hip/hip_runtime.h>

#define N_NODE 2048
#define D_DIM 64
#define ND ((size_t)N_NODE * (size_t)D_DIM)   // 131072 floats per (b,l) frame
#define L_SEQ 12

using s16x8 = __attribute__((ext_vector_type(8))) short;
using s16x4 = __attribute__((ext_vector_type(4))) short;
using f32x4 = __attribute__((ext_vector_type(4))) float;

__device__ __forceinline__ float relu_f(float x) { return fmaxf(x, 0.f); }

// f32 -> bf16 bits, round-to-nearest-even (finite data only)
__device__ __forceinline__ unsigned short f2bf(float f) {
    unsigned u = __float_as_uint(f);
    return (unsigned short)((u + 0x7FFFu + ((u >> 16) & 1u)) >> 16);
}

// LDS tile layout: [row][32 k] bf16, 64B rows; 16B slot XOR-swizzled so that
// both the staging ds_write_b128 and the fragment ds_read_b128 are <=2-way.
__device__ __forceinline__ int swz_off(int row, int slot) {
    return row * 32 + ((slot ^ ((row >> 2) & 3)) << 3);
}

// ---------------------------------------------------------------------------
// K0: convert G -> Ag = bf16(G) row-major, and BTg[n][k] = bf16(G[k][n]*(k!=n))
// (B^T for the build GEMM). 64x64 tiles, LDS transpose.
// ---------------------------------------------------------------------------
__global__ __launch_bounds__(256) void k_conv(const float* __restrict__ G,
                                              unsigned short* __restrict__ Ag,
                                              unsigned short* __restrict__ BTg) {
    __shared__ float T[64][65];
    const int tid = threadIdx.x;
    const int c0 = blockIdx.x * 64;
    const int r0 = blockIdx.y * 64;
    #pragma unroll
    for (int p = 0; p < 4; ++p) {
        const int g = tid + p * 256;
        const int row = g >> 4;
        const int c4 = (g & 15) * 4;
        const float4 v = *(const float4*)(G + (size_t)(r0 + row) * N_NODE + c0 + c4);
        s16x4 a;
        a[0] = (short)f2bf(v.x); a[1] = (short)f2bf(v.y);
        a[2] = (short)f2bf(v.z); a[3] = (short)f2bf(v.w);
        *(s16x4*)(Ag + (size_t)(r0 + row) * N_NODE + c0 + c4) = a;
        const int gr = r0 + row;
        T[c4 + 0][row] = (gr == c0 + c4 + 0) ? 0.f : v.x;
        T[c4 + 1][row] = (gr == c0 + c4 + 1) ? 0.f : v.y;
        T[c4 + 2][row] = (gr == c0 + c4 + 2) ? 0.f : v.z;
        T[c4 + 3][row] = (gr == c0 + c4 + 3) ? 0.f : v.w;
    }
    __syncthreads();
    #pragma unroll
    for (int p = 0; p < 4; ++p) {
        const int g = tid + p * 256;
        const int orow = g >> 4;          // BT row = original col
        const int oc4 = (g & 15) * 4;     // BT col = original row (k)
        s16x4 o;
        o[0] = (short)f2bf(T[orow][oc4 + 0]);
        o[1] = (short)f2bf(T[orow][oc4 + 1]);
        o[2] = (short)f2bf(T[orow][oc4 + 2]);
        o[3] = (short)f2bf(T[orow][oc4 + 3]);
        *(s16x4*)(BTg + (size_t)(c0 + orow) * N_NODE + r0 + oc4) = o;
    }
}

// ---------------------------------------------------------------------------
// K1: Gsum_eff = bf16( mask*(G + G@Gm) + I/3 ).  MFMA 128x128 tile, 4 waves.
// A = Ag row-major, B^T = BTg row-major. BK=32.
// ---------------------------------------------------------------------------
__global__ __launch_bounds__(256) void k_build(const unsigned short* __restrict__ Ag,
                                               const unsigned short* __restrict__ BTg,
                                               const float* __restrict__ G,
                                               unsigned short* __restrict__ Gsum) {
    __shared__ short Asm[128 * 32];
    __shared__ short Bsm[128 * 32];
    const int tid = threadIdx.x;
    const int n0 = blockIdx.x * 128;
    const int m0 = blockIdx.y * 128;
    const int lane = tid & 63;
    const int w = tid >> 6;
    const int wm = (w & 1) * 64;
    const int wn = (w >> 1) * 64;
    const int lr = lane & 15;
    const int lk = lane >> 4;
    const int srow = tid >> 2;          // staging: granule row 0..63 (+64)
    const int sslot = tid & 3;

    f32x4 acc[4][4] = {};
    s16x8 ra0, ra1, rb0, rb1;
    // prologue loads (k0 = 0)
    ra0 = *(const s16x8*)(Ag + (size_t)(m0 + srow) * N_NODE + sslot * 8);
    ra1 = *(const s16x8*)(Ag + (size_t)(m0 + srow + 64) * N_NODE + sslot * 8);
    rb0 = *(const s16x8*)(BTg + (size_t)(n0 + srow) * N_NODE + sslot * 8);
    rb1 = *(const s16x8*)(BTg + (size_t)(n0 + srow + 64) * N_NODE + sslot * 8);

    for (int k0 = 0; k0 < N_NODE; k0 += 32) {
        __syncthreads();
        *(s16x8*)&Asm[swz_off(srow, sslot)] = ra0;
        *(s16x8*)&Asm[swz_off(srow + 64, sslot)] = ra1;
        *(s16x8*)&Bsm[swz_off(srow, sslot)] = rb0;
        *(s16x8*)&Bsm[swz_off(srow + 64, sslot)] = rb1;
        __syncthreads();
        if (k0 + 32 < N_NODE) {
            const int kn = k0 + 32;
            ra0 = *(const s16x8*)(Ag + (size_t)(m0 + srow) * N_NODE + kn + sslot * 8);
            ra1 = *(const s16x8*)(Ag + (size_t)(m0 + srow + 64) * N_NODE + kn + sslot * 8);
            rb0 = *(const s16x8*)(BTg + (size_t)(n0 + srow) * N_NODE + kn + sslot * 8);
            rb1 = *(const s16x8*)(BTg + (size_t)(n0 + srow + 64) * N_NODE + kn + sslot * 8);
        }
        s16x8 af[4], bfr[4];
        #pragma unroll
        for (int fr = 0; fr < 4; ++fr)
            af[fr] = *(const s16x8*)&Asm[swz_off(wm + fr * 16 + lr, lk)];
        #pragma unroll
        for (int fc = 0; fc < 4; ++fc)
            bfr[fc] = *(const s16x8*)&Bsm[swz_off(wn + fc * 16 + lr, lk)];
        #pragma unroll
        for (int fr = 0; fr < 4; ++fr)
            #pragma unroll
            for (int fc = 0; fc < 4; ++fc)
                acc[fr][fc] = __builtin_amdgcn_mfma_f32_16x16x32_bf16(
                    af[fr], bfr[fc], acc[fr][fc], 0, 0, 0);
    }
    // epilogue: Gsum_eff = bf16(acc + G), diag = 1/3
    #pragma unroll
    for (int fc = 0; fc < 4; ++fc) {
        const int n = n0 + wn + fc * 16 + lr;
        #pragma unroll
        for (int fr = 0; fr < 4; ++fr) {
            #pragma unroll
            for (int reg = 0; reg < 4; ++reg) {
                const int m = m0 + wm + fr * 16 + lk * 4 + reg;
                const float v = acc[fr][fc][reg] + G[(size_t)m * N_NODE + n];
                Gsum[(size_t)m * N_NODE + n] =
                    (m == n) ? f2bf(1.f / 3.f) : f2bf(v);
            }
        }
    }
}

// ---------------------------------------------------------------------------
// K2: FC + GCN-fold.  Per (n-tile, bt): h = relu(Xw@W_fc); Xs = sum_kt h;
// Y = Xs @ W_gcn; write Y^T bf16 [64 d][2048 n] per bt.
// ---------------------------------------------------------------------------
__global__ __launch_bounds__(256) void k_fc(const float* __restrict__ f0,
                                            const float* __restrict__ f1,
                                            const float* __restrict__ f2,
                                            const float* __restrict__ W_fc,
                                            const float* __restrict__ W_gcn,
                                            unsigned short* __restrict__ YT,
                                            int t_count) {
    __shared__ float smem[64 * 64 + 64 * 192];   // 64 KB, re-aliased per phase
    float* Ast = smem;          // [64][64]: Ast[k*64 + r]
    float* Bs = smem + 4096;    // [64][192]
    const int tid = threadIdx.x;
    const int n0 = blockIdx.x * 64;
    const int bt = blockIdx.y;
    const int b = bt / t_count;
    const int t = bt % t_count;
    const size_t fr = (size_t)b * L_SEQ * ND + (size_t)t * ND + (size_t)n0 * D_DIM;
    const float* frames[3] = {f0 + fr, f1 + fr, f2 + fr};
    const int lrow = tid >> 4;
    const int lc4 = (tid & 15) * 4;
    const int r0 = (tid >> 4) * 4;
    const int c0 = (tid & 15) * 4;

    // stash W_gcn in registers (written to LDS after the main loop)
    float wg[16];
    #pragma unroll
    for (int p = 0; p < 16; ++p) wg[p] = W_gcn[tid + p * 256];

    float acc[3][4][4] = {};
    #pragma unroll
    for (int kk = 0; kk < 3; ++kk) {
        const float* F = frames[kk];
        #pragma unroll
        for (int p = 0; p < 4; ++p) {
            const int r = lrow + p * 16;
            const float4 v = *(const float4*)(F + (size_t)r * D_DIM + lc4);
            Ast[(lc4 + 0) * 64 + r] = v.x;
            Ast[(lc4 + 1) * 64 + r] = v.y;
            Ast[(lc4 + 2) * 64 + r] = v.z;
            Ast[(lc4 + 3) * 64 + r] = v.w;
        }
        #pragma unroll
        for (int p = 0; p < 12; ++p) {
            const int f4i = tid + p * 256;
            const int row = f4i / 48;
            const int c4 = (f4i % 48) * 4;
            *(float4*)&Bs[row * 192 + c4] =
                *(const float4*)(W_fc + (size_t)(kk * 64 + row) * 192 + c4);
        }
        __syncthreads();
        #pragma unroll 4
        for (int k = 0; k < 64; ++k) {
            const float4 a4 = *(const float4*)&Ast[k * 64 + r0];
            const float a_[4] = {a4.x, a4.y, a4.z, a4.w};
            #pragma unroll
            for (int jc = 0; jc < 3; ++jc) {
                const float4 w4 = *(const float4*)&Bs[k * 192 + jc * 64 + c0];
                const float w_[4] = {w4.x, w4.y, w4.z, w4.w};
                #pragma unroll
                for (int i = 0; i < 4; ++i)
                    #pragma unroll
                    for (int j = 0; j < 4; ++j)
                        acc[jc][i][j] = fmaf(a_[i], w_[j], acc[jc][i][j]);
            }
        }
        __syncthreads();
    }
    // phase 2: Xs tile + W_gcn into LDS
    float* XsS = smem;          // [64][65]
    float* WgS = smem + 4160;   // [64][65]
    float* YtS = smem + 8320;   // [64][65]
    #pragma unroll
    for (int i = 0; i < 4; ++i)
        #pragma unroll
        for (int j = 0; j < 4; ++j)
            XsS[(r0 + i) * 65 + c0 + j] = relu_f(acc[0][i][j]) +
                                          relu_f(acc[1][i][j]) +
                                          relu_f(acc[2][i][j]);
    #pragma unroll
    for (int p = 0; p < 16; ++p) {
        const int e = tid + p * 256;
        WgS[(e >> 6) * 65 + (e & 63)] = wg[p];
    }
    __syncthreads();
    // Y = Xs @ W_gcn
    float y[4][4] = {};
    #pragma unroll 8
    for (int k = 0; k < 64; ++k) {
        const float a_[4] = {XsS[(r0 + 0) * 65 + k], XsS[(r0 + 1) * 65 + k],
                             XsS[(r0 + 2) * 65 + k], XsS[(r0 + 3) * 65 + k]};
        const float4 w4 = *(const float4*)&WgS[k * 65 + c0];
        const float w_[4] = {w4.x, w4.y, w4.z, w4.w};
        #pragma unroll
        for (int i = 0; i < 4; ++i)
            #pragma unroll
            for (int j = 0; j < 4; ++j)
                y[i][j] = fmaf(a_[i], w_[j], y[i][j]);
    }
    #pragma unroll
    for (int i = 0; i < 4; ++i)
        #pragma unroll
        for (int j = 0; j < 4; ++j)
            YtS[(c0 + j) * 65 + r0 + i] = y[i][j];
    __syncthreads();
    // write Y^T bf16, coalesced
    const int d = tid >> 2;
    const int seg = tid & 3;
    unsigned short* dst = YT + ((size_t)bt * 64 + d) * N_NODE + n0 + seg * 16;
    s16x8 o0, o1;
    #pragma unroll
    for (int q = 0; q < 8; ++q) {
        o0[q] = (short)f2bf(YtS[d * 65 + seg * 16 + q]);
        o1[q] = (short)f2bf(YtS[d * 65 + seg * 16 + 8 + q]);
    }
    *(s16x8*)dst = o0;
    *(s16x8*)(dst + 8) = o1;
}

// ---------------------------------------------------------------------------
// K3: out[bt] = Gsum_eff @ Y[bt] + b_gcn.   MFMA, 128 rows x 2 bt per block.
// ---------------------------------------------------------------------------
__global__ __launch_bounds__(256) void k_prop(const unsigned short* __restrict__ Gsum,
                                              const unsigned short* __restrict__ YT,
                                              const float* __restrict__ b_gcn,
                                              float* __restrict__ out_base,
                                              long long bt_stride,
                                              float* __restrict__ p0_base) {
    __shared__ short Asm[128 * 32];
    __shared__ short Bsm[128 * 32];
    const int tid = threadIdx.x;
    const int m0 = blockIdx.x * 128;
    const int bt0 = blockIdx.y * 2;
    const int lane = tid & 63;
    const int w = tid >> 6;
    const int wm = (w & 1) * 64;
    const int wn = (w >> 1) * 64;
    const int lr = lane & 15;
    const int lk = lane >> 4;
    const int srow = tid >> 2;
    const int sslot = tid & 3;
    const unsigned short* Yb0 = YT + (size_t)bt0 * 64 * N_NODE;       // bt0, rows 0..63
    const unsigned short* Yb1 = YT + (size_t)(bt0 + 1) * 64 * N_NODE; // bt0+1

    f32x4 acc[4][4] = {};
    s16x8 ra0, ra1, rb0, rb1;
    ra0 = *(const s16x8*)(Gsum + (size_t)(m0 + srow) * N_NODE + sslot * 8);
    ra1 = *(const s16x8*)(Gsum + (size_t)(m0 + srow + 64) * N_NODE + sslot * 8);
    rb0 = *(const s16x8*)(Yb0 + (size_t)srow * N_NODE + sslot * 8);
    rb1 = *(const s16x8*)(Yb1 + (size_t)srow * N_NODE + sslot * 8);

    for (int k0 = 0; k0 < N_NODE; k0 += 32) {
        __syncthreads();
        *(s16x8*)&Asm[swz_off(srow, sslot)] = ra0;
        *(s16x8*)&Asm[swz_off(srow + 64, sslot)] = ra1;
        *(s16x8*)&Bsm[swz_off(srow, sslot)] = rb0;
        *(s16x8*)&Bsm[swz_off(srow + 64, sslot)] = rb1;
        __syncthreads();
        if (k0 + 32 < N_NODE) {
            const int kn = k0 + 32;
            ra0 = *(const s16x8*)(Gsum + (size_t)(m0 + srow) * N_NODE + kn + sslot * 8);
            ra1 = *(const s16x8*)(Gsum + (size_t)(m0 + srow + 64) * N_NODE + kn + sslot * 8);
            rb0 = *(const s16x8*)(Yb0 + (size_t)srow * N_NODE + kn + sslot * 8);
            rb1 = *(const s16x8*)(Yb1 + (size_t)srow * N_NODE + kn + sslot * 8);
        }
        s16x8 af[4], bfr[4];
        #pragma unroll
        for (int fr = 0; fr < 4; ++fr)
            af[fr] = *(const s16x8*)&Asm[swz_off(wm + fr * 16 + lr, lk)];
        #pragma unroll
        for (int fc = 0; fc < 4; ++fc)
            bfr[fc] = *(const s16x8*)&Bsm[swz_off(wn + fc * 16 + lr, lk)];
        #pragma unroll
        for (int fr = 0; fr < 4; ++fr)
            #pragma unroll
            for (int fc = 0; fc < 4; ++fc)
                acc[fr][fc] = __builtin_amdgcn_mfma_f32_16x16x32_bf16(
                    af[fr], bfr[fc], acc[fr][fc], 0, 0, 0);
    }
    #pragma unroll
    for (int fc = 0; fc < 4; ++fc) {
        const int col = wn + fc * 16 + lr;          // 0..127
        const int btg = bt0 + (col >> 6);
        const int d = col & 63;
        const float bias = b_gcn[d];
        float* op = out_base + (size_t)btg * (size_t)bt_stride;
        float* pp = nullptr;
        if (p0_base != nullptr && (btg % 10) == 9)
            pp = p0_base + (size_t)(btg / 10) * ((size_t)L_SEQ * ND);
        #pragma unroll
        for (int frr = 0; frr < 4; ++frr) {
            const int mb = m0 + wm + frr * 16 + lk * 4;
            #pragma unroll
            for (int reg = 0; reg < 4; ++reg) {
                const size_t off = (size_t)(mb + reg) * D_DIM + d;
                const float v = acc[frr][fc][reg] + bias;
                op[off] = v;
                if (pp) pp[off] = v;
            }
        }
    }
}

// ---------------------------------------------------------------------------
// K4: forecast = P @ W_fore + b_fore (f32 VALU).
// ---------------------------------------------------------------------------
__global__ __launch_bounds__(256) void k_forecast(const float* __restrict__ P,
                                                  const float* __restrict__ W_fore,
                                                  const float* __restrict__ b_fore,
                                                  float* __restrict__ out) {
    __shared__ float Ast[64][64];
    const int tid = threadIdx.x;
    const size_t row0 = (size_t)blockIdx.x * 64;
    const int lrow = tid >> 4;
    const int lc4 = (tid & 15) * 4;
    const int r0 = (tid >> 4) * 4;
    const int c0 = (tid & 15) * 4;
    #pragma unroll
    for (int p = 0; p < 4; ++p) {
        const int r = lrow + p * 16;
        const float4 v = *(const float4*)(P + (row0 + r) * D_DIM + lc4);
        Ast[lc4 + 0][r] = v.x;
        Ast[lc4 + 1][r] = v.y;
        Ast[lc4 + 2][r] = v.z;
        Ast[lc4 + 3][r] = v.w;
    }
    __syncthreads();
    float acc[4][4][4];
    #pragma unroll
    for (int jc = 0; jc < 4; ++jc) {
        const float4 bb = *(const float4*)(b_fore + jc * 64 + c0);
        #pragma unroll
        for (int i = 0; i < 4; ++i) {
            acc[jc][i][0] = bb.x; acc[jc][i][1] = bb.y;
            acc[jc][i][2] = bb.z; acc[jc][i][3] = bb.w;
        }
    }
    #pragma unroll 4
    for (int k = 0; k < 64; ++k) {
        const float4 a4 = *(const float4*)&Ast[k][r0];
        const float a_[4] = {a4.x, a4.y, a4.z, a4.w};
        #pragma unroll
        for (int jc = 0; jc < 4; ++jc) {
            const float4 w4 = *(const float4*)(W_fore + (size_t)k * 256 + jc * 64 + c0);
            const float w_[4] = {w4.x, w4.y, w4.z, w4.w};
            #pragma unroll
            for (int i = 0; i < 4; ++i)
                #pragma unroll
                for (int j = 0; j < 4; ++j)
                    acc[jc][i][j] = fmaf(a_[i], w_[j], acc[jc][i][j]);
        }
    }
    #pragma unroll
    for (int i = 0; i < 4; ++i)
        #pragma unroll
        for (int jc = 0; jc < 4; ++jc) {
            float4 o;
            o.x = acc[jc][i][0]; o.y = acc[jc][i][1];
            o.z = acc[jc][i][2]; o.w = acc[jc][i][3];
            *(float4*)(out + (row0 + r0 + i) * 256 + jc * 64 + c0) = o;
        }
}

// ---------------------------------------------------------------------------
// K5: backcast = LN(X[:,2:] - relu(Z @ W_back + b_back)).
// ---------------------------------------------------------------------------
__global__ __launch_bounds__(256) void k_backcast(const float* __restrict__ Z,
                                                  const float* __restrict__ X,
                                                  const float* __restrict__ W_back,
                                                  const float* __restrict__ b_back,
                                                  const float* __restrict__ gamma,
                                                  const float* __restrict__ beta,
                                                  float* __restrict__ out) {
    const int tid = threadIdx.x;
    const int lane = tid & 63;
    const int wid = tid >> 6;
    const size_t row = (size_t)blockIdx.x * 4 + wid;
    const int bt = (int)(row >> 11);
    const int b = bt / 10;
    const int t = bt % 10;
    const size_t n = row & 2047;
    const float z = Z[row * D_DIM + lane];
    float back = b_back[lane];
    #pragma unroll 8
    for (int k = 0; k < 64; ++k) {
        const float zk = __shfl(z, k, 64);
        back = fmaf(zk, W_back[k * D_DIM + lane], back);
    }
    const float xr = X[(((size_t)b * L_SEQ + t + 2) * N_NODE + n) * D_DIM + lane];
    const float u = xr - fmaxf(back, 0.f);
    float s = u;
    #pragma unroll
    for (int off = 32; off > 0; off >>= 1) s += __shfl_xor(s, off, 64);
    const float mu = s * (1.f / 64.f);
    const float dv = u - mu;
    float s2 = dv * dv;
    #pragma unroll
    for (int off = 32; off > 0; off >>= 1) s2 += __shfl_xor(s2, off, 64);
    const float var = s2 * (1.f / 64.f);
    out[row * D_DIM + lane] = dv * rsqrtf(var + 1e-5f) * gamma[lane] + beta[lane];
}

// ---------------------------------------------------------------------------
extern "C" void kernel_launch(void* const* d_in, const int* in_sizes, int n_in,
                              void* d_out, int out_size, void* d_ws, size_t ws_size,
                              hipStream_t stream) {
    (void)in_sizes; (void)n_in; (void)out_size; (void)ws_size;
    const float* X      = (const float*)d_in[0];
    const float* X_spa  = (const float*)d_in[1];
    const float* G      = (const float*)d_in[2];
    const float* W_fc   = (const float*)d_in[3];
    const float* W_gcn  = (const float*)d_in[4];
    const float* b_gcn  = (const float*)d_in[5];
    const float* W_fore = (const float*)d_in[6];
    const float* b_fore = (const float*)d_in[7];
    const float* W_back = (const float*)d_in[8];
    const float* b_back = (const float*)d_in[9];
    const float* gamma  = (const float*)d_in[10];
    const float* beta   = (const float*)d_in[11];

    float* backcast = (float*)d_out;                      // 4*10*2048*64
    float* forecast = (float*)d_out + (size_t)5242880;    // 4*12*2048*256

    // workspace (80 MB total, every byte written before read)
    char* wsb = (char*)d_ws;
    unsigned short* Gsum = (unsigned short*)wsb;                      //  8 MB
    unsigned short* Ag   = (unsigned short*)(wsb + ((size_t)8 << 20));  //  8 MB
    unsigned short* BTg  = (unsigned short*)(wsb + ((size_t)16 << 20)); //  8 MB
    unsigned short* YTb  = (unsigned short*)(wsb + ((size_t)24 << 20)); // 10 MB (40 bt)
    unsigned short* YTs  = (unsigned short*)(wsb + ((size_t)35 << 20)); //  1 MB (4 bt)
    float* Z             = (float*)(wsb + ((size_t)36 << 20));          // 20 MB
    float* P             = (float*)(wsb + ((size_t)56 << 20));          // 24 MB

    const dim3 blk(256);

    k_conv<<<dim3(32, 32), blk, 0, stream>>>(G, Ag, BTg);
    k_build<<<dim3(16, 16), blk, 0, stream>>>(Ag, BTg, G, Gsum);

    // Stage B: t=0..9 over 4 batches (40 bt)
    k_fc<<<dim3(32, 40), blk, 0, stream>>>(X_spa, X_spa + ND, X_spa + 2 * ND,
                                           W_fc, W_gcn, YTb, 10);
    k_prop<<<dim3(16, 20), blk, 0, stream>>>(Gsum, YTb, b_gcn,
                                             Z, (long long)ND, P);

    // Stage C: 11 serial autoregressive steps (4 bt each)
    for (int i = 1; i <= 11; ++i) {
        const float *f0, *f1, *f2;
        if (i == 1)      { f0 = X_spa + 10 * ND; f1 = X_spa + 11 * ND; f2 = P; }
        else if (i == 2) { f0 = X_spa + 11 * ND; f1 = P;               f2 = P + ND; }
        else             { f0 = P + (size_t)(i - 3) * ND;
                           f1 = P + (size_t)(i - 2) * ND;
                           f2 = P + (size_t)(i - 1) * ND; }
        k_fc<<<dim3(32, 4), blk, 0, stream>>>(f0, f1, f2, W_fc, W_gcn, YTs, 1);
        k_prop<<<dim3(16, 2), blk, 0, stream>>>(Gsum, YTs, b_gcn,
                                                P + (size_t)i * ND,
                                                (long long)(L_SEQ * ND), nullptr);
    }

    k_forecast<<<dim3(1536), blk, 0, stream>>>(P, W_fore, b_fore, forecast);
    k_backcast<<<dim3(20480), blk, 0, stream>>>(Z, X, W_back, b_back,
                                                gamma, beta, backcast);
}

// Round 3
// 673.337 us; speedup vs baseline: 3.3199x; 1.8066x over previous
//
#include <hip/hip_runtime.h>

#define N_NODE 2048
#define D_DIM 64
#define ND ((size_t)N_NODE * (size_t)D_DIM)   // 131072 floats per (b,l) frame
#define L_SEQ 12

using s16x8 = __attribute__((ext_vector_type(8))) short;
using s16x4 = __attribute__((ext_vector_type(4))) short;
using f32x4 = __attribute__((ext_vector_type(4))) float;

__device__ __forceinline__ float relu_f(float x) { return fmaxf(x, 0.f); }

// f32 -> bf16 bits, round-to-nearest-even (finite data only)
__device__ __forceinline__ unsigned short f2bf(float f) {
    unsigned u = __float_as_uint(f);
    return (unsigned short)((u + 0x7FFFu + ((u >> 16) & 1u)) >> 16);
}

// LDS tile layout for 128x32 bf16 tiles: [row][32 k], 16B slot XOR-swizzle.
__device__ __forceinline__ int swz_off(int row, int slot) {
    return row * 32 + ((slot ^ ((row >> 2) & 3)) << 3);
}

// ---------------------------------------------------------------------------
// K_wprep: WfcT[c][k] = bf16(W_fc[k][c]) (192x192); WgT[c][k] = bf16(W_gcn[k][c])
// ---------------------------------------------------------------------------
__global__ __launch_bounds__(256) void k_wprep(const float* __restrict__ W_fc,
                                               const float* __restrict__ W_gcn,
                                               unsigned short* __restrict__ WfcT,
                                               unsigned short* __restrict__ WgT) {
    const int i = blockIdx.x * 256 + threadIdx.x;
    if (i < 192 * 192) {
        const int c = i / 192, k = i % 192;
        WfcT[i] = f2bf(W_fc[(size_t)k * 192 + c]);
    } else if (i < 192 * 192 + 64 * 64) {
        const int j = i - 192 * 192;
        const int c = j / 64, k = j % 64;
        WgT[j] = f2bf(W_gcn[(size_t)k * 64 + c]);
    }
}

// ---------------------------------------------------------------------------
// K0: G -> Ag = bf16(G) row-major, BTg[n][k] = bf16(G[k][n]*(k!=n))
// ---------------------------------------------------------------------------
__global__ __launch_bounds__(256) void k_conv(const float* __restrict__ G,
                                              unsigned short* __restrict__ Ag,
                                              unsigned short* __restrict__ BTg) {
    __shared__ float T[64][65];
    const int tid = threadIdx.x;
    const int c0 = blockIdx.x * 64;
    const int r0 = blockIdx.y * 64;
    #pragma unroll
    for (int p = 0; p < 4; ++p) {
        const int g = tid + p * 256;
        const int row = g >> 4;
        const int c4 = (g & 15) * 4;
        const float4 v = *(const float4*)(G + (size_t)(r0 + row) * N_NODE + c0 + c4);
        s16x4 a;
        a[0] = (short)f2bf(v.x); a[1] = (short)f2bf(v.y);
        a[2] = (short)f2bf(v.z); a[3] = (short)f2bf(v.w);
        *(s16x4*)(Ag + (size_t)(r0 + row) * N_NODE + c0 + c4) = a;
        const int gr = r0 + row;
        T[c4 + 0][row] = (gr == c0 + c4 + 0) ? 0.f : v.x;
        T[c4 + 1][row] = (gr == c0 + c4 + 1) ? 0.f : v.y;
        T[c4 + 2][row] = (gr == c0 + c4 + 2) ? 0.f : v.z;
        T[c4 + 3][row] = (gr == c0 + c4 + 3) ? 0.f : v.w;
    }
    __syncthreads();
    #pragma unroll
    for (int p = 0; p < 4; ++p) {
        const int g = tid + p * 256;
        const int orow = g >> 4;
        const int oc4 = (g & 15) * 4;
        s16x4 o;
        o[0] = (short)f2bf(T[orow][oc4 + 0]);
        o[1] = (short)f2bf(T[orow][oc4 + 1]);
        o[2] = (short)f2bf(T[orow][oc4 + 2]);
        o[3] = (short)f2bf(T[orow][oc4 + 3]);
        *(s16x4*)(BTg + (size_t)(c0 + orow) * N_NODE + r0 + oc4) = o;
    }
}

// ---------------------------------------------------------------------------
// K1: Gsum_eff = bf16( mask*(G + G@Gm) + I/3 ).  MFMA 128x128 tile, 4 waves.
// ---------------------------------------------------------------------------
__global__ __launch_bounds__(256) void k_build(const unsigned short* __restrict__ Ag,
                                               const unsigned short* __restrict__ BTg,
                                               const float* __restrict__ G,
                                               unsigned short* __restrict__ Gsum) {
    __shared__ short Asm[128 * 32];
    __shared__ short Bsm[128 * 32];
    const int tid = threadIdx.x;
    const int n0 = blockIdx.x * 128;
    const int m0 = blockIdx.y * 128;
    const int lane = tid & 63;
    const int w = tid >> 6;
    const int wm = (w & 1) * 64;
    const int wn = (w >> 1) * 64;
    const int lr = lane & 15;
    const int lk = lane >> 4;
    const int srow = tid >> 2;
    const int sslot = tid & 3;

    f32x4 acc[4][4] = {};
    s16x8 ra0, ra1, rb0, rb1;
    ra0 = *(const s16x8*)(Ag + (size_t)(m0 + srow) * N_NODE + sslot * 8);
    ra1 = *(const s16x8*)(Ag + (size_t)(m0 + srow + 64) * N_NODE + sslot * 8);
    rb0 = *(const s16x8*)(BTg + (size_t)(n0 + srow) * N_NODE + sslot * 8);
    rb1 = *(const s16x8*)(BTg + (size_t)(n0 + srow + 64) * N_NODE + sslot * 8);

    for (int k0 = 0; k0 < N_NODE; k0 += 32) {
        __syncthreads();
        *(s16x8*)&Asm[swz_off(srow, sslot)] = ra0;
        *(s16x8*)&Asm[swz_off(srow + 64, sslot)] = ra1;
        *(s16x8*)&Bsm[swz_off(srow, sslot)] = rb0;
        *(s16x8*)&Bsm[swz_off(srow + 64, sslot)] = rb1;
        __syncthreads();
        if (k0 + 32 < N_NODE) {
            const int kn = k0 + 32;
            ra0 = *(const s16x8*)(Ag + (size_t)(m0 + srow) * N_NODE + kn + sslot * 8);
            ra1 = *(const s16x8*)(Ag + (size_t)(m0 + srow + 64) * N_NODE + kn + sslot * 8);
            rb0 = *(const s16x8*)(BTg + (size_t)(n0 + srow) * N_NODE + kn + sslot * 8);
            rb1 = *(const s16x8*)(BTg + (size_t)(n0 + srow + 64) * N_NODE + kn + sslot * 8);
        }
        s16x8 af[4], bfr[4];
        #pragma unroll
        for (int fr = 0; fr < 4; ++fr)
            af[fr] = *(const s16x8*)&Asm[swz_off(wm + fr * 16 + lr, lk)];
        #pragma unroll
        for (int fc = 0; fc < 4; ++fc)
            bfr[fc] = *(const s16x8*)&Bsm[swz_off(wn + fc * 16 + lr, lk)];
        #pragma unroll
        for (int fr = 0; fr < 4; ++fr)
            #pragma unroll
            for (int fc = 0; fc < 4; ++fc)
                acc[fr][fc] = __builtin_amdgcn_mfma_f32_16x16x32_bf16(
                    af[fr], bfr[fc], acc[fr][fc], 0, 0, 0);
    }
    #pragma unroll
    for (int fc = 0; fc < 4; ++fc) {
        const int n = n0 + wn + fc * 16 + lr;
        #pragma unroll
        for (int fr = 0; fr < 4; ++fr) {
            #pragma unroll
            for (int reg = 0; reg < 4; ++reg) {
                const int m = m0 + wm + fr * 16 + lk * 4 + reg;
                const float v = acc[fr][fc][reg] + G[(size_t)m * N_NODE + n];
                Gsum[(size_t)m * N_NODE + n] =
                    (m == n) ? f2bf(1.f / 3.f) : f2bf(v);
            }
        }
    }
}

// ---------------------------------------------------------------------------
// K2 (MFMA): per (n-tile 64, bt):
//   h = relu(bf16(Xw) @ W_fc)  [64 x 192]   (MFMA, K=192)
//   Xs = sum over 3 kt groups of h
//   Y  = Xs @ W_gcn                          (MFMA, K=64)
//   write Y^T bf16 [64 d][2048 n]
// ---------------------------------------------------------------------------
__global__ __launch_bounds__(256) void k_fc(const float* __restrict__ f0,
                                            const float* __restrict__ f1,
                                            const float* __restrict__ f2,
                                            const unsigned short* __restrict__ WfcT,
                                            const unsigned short* __restrict__ WgT,
                                            unsigned short* __restrict__ YT,
                                            int t_count) {
    __shared__ __align__(16) char smem[56320];
    short* As = (short*)smem;                 // [64][200] bf16  (25600 B)
    short* Bb = (short*)(smem + 25600);       // [2][192][40] bf16 (30720 B)
    float* Hs = (float*)smem;                 // [64][197] f32 (phase 2, 50432 B)
    short* Xs = (short*)smem;                 // [64][72] bf16 (phase 3/4)
    short* Wg = (short*)(smem + 9216);        // [64][72] bf16

    const int tid = threadIdx.x;
    const int n0 = blockIdx.x * 64;
    const int bt = blockIdx.y;
    const int b = bt / t_count, t = bt % t_count;
    const size_t base = (size_t)b * L_SEQ * ND + (size_t)t * ND + (size_t)n0 * D_DIM;
    const float* frames[3] = {f0 + base, f1 + base, f2 + base};
    const int lane = tid & 63;
    const int w = tid >> 6;        // 4 waves; wave covers all 64 rows x 48 cols
    const int wn = w * 48;
    const int lr = lane & 15;
    const int lk = lane >> 4;

    // stage A: 64 rows x 192 K, bf16
    #pragma unroll
    for (int p = 0; p < 12; ++p) {
        const int kk = p >> 2;
        const int e = tid + (p & 3) * 256;
        const int row = e >> 4;
        const int c4 = (e & 15) * 4;
        const float4 v = *(const float4*)(frames[kk] + (size_t)row * 64 + c4);
        s16x4 a;
        a[0] = (short)f2bf(v.x); a[1] = (short)f2bf(v.y);
        a[2] = (short)f2bf(v.z); a[3] = (short)f2bf(v.w);
        *(s16x4*)&As[row * 200 + kk * 64 + c4] = a;
    }
    // stage B chunk 0 (W_fc^T cols x 32 k)
    #pragma unroll
    for (int p = 0; p < 3; ++p) {
        const int g = tid + p * 256;
        const int c = g >> 2, slot = g & 3;
        *(s16x8*)&Bb[c * 40 + slot * 8] =
            *(const s16x8*)(WfcT + (size_t)c * 192 + slot * 8);
    }
    __syncthreads();

    f32x4 acc[4][3] = {};
    for (int kc = 0; kc < 6; ++kc) {
        const int cur = kc & 1;
        s16x8 nb[3];
        if (kc < 5) {
            #pragma unroll
            for (int p = 0; p < 3; ++p) {
                const int g = tid + p * 256;
                const int c = g >> 2, slot = g & 3;
                nb[p] = *(const s16x8*)(WfcT + (size_t)c * 192 + (kc + 1) * 32 + slot * 8);
            }
        }
        s16x8 af[4], bf_[3];
        #pragma unroll
        for (int fr = 0; fr < 4; ++fr)
            af[fr] = *(const s16x8*)&As[(fr * 16 + lr) * 200 + kc * 32 + lk * 8];
        #pragma unroll
        for (int fc = 0; fc < 3; ++fc)
            bf_[fc] = *(const s16x8*)&Bb[cur * 7680 + (wn + fc * 16 + lr) * 40 + lk * 8];
        #pragma unroll
        for (int fr = 0; fr < 4; ++fr)
            #pragma unroll
            for (int fc = 0; fc < 3; ++fc)
                acc[fr][fc] = __builtin_amdgcn_mfma_f32_16x16x32_bf16(
                    af[fr], bf_[fc], acc[fr][fc], 0, 0, 0);
        if (kc < 5) {
            #pragma unroll
            for (int p = 0; p < 3; ++p) {
                const int g = tid + p * 256;
                const int c = g >> 2, slot = g & 3;
                *(s16x8*)&Bb[(cur ^ 1) * 7680 + c * 40 + slot * 8] = nb[p];
            }
        }
        __syncthreads();
    }
    // phase 2: relu(h) -> LDS [64][197] f32
    #pragma unroll
    for (int fr = 0; fr < 4; ++fr)
        #pragma unroll
        for (int fc = 0; fc < 3; ++fc)
            #pragma unroll
            for (int reg = 0; reg < 4; ++reg) {
                const int row = fr * 16 + lk * 4 + reg;
                const int col = wn + fc * 16 + lr;
                Hs[row * 197 + col] = fmaxf(acc[fr][fc][reg], 0.f);
            }
    __syncthreads();
    // phase 3: Xs = kt-sum into regs, then bf16 LDS; stage WgT
    const int xn = tid >> 2;
    const int d0 = (tid & 3) * 16;
    float xsv[16];
    #pragma unroll
    for (int q = 0; q < 16; ++q)
        xsv[q] = Hs[xn * 197 + d0 + q] + Hs[xn * 197 + 64 + d0 + q] +
                 Hs[xn * 197 + 128 + d0 + q];
    __syncthreads();
    #pragma unroll
    for (int q2 = 0; q2 < 4; ++q2) {
        s16x4 a;
        a[0] = (short)f2bf(xsv[q2 * 4 + 0]); a[1] = (short)f2bf(xsv[q2 * 4 + 1]);
        a[2] = (short)f2bf(xsv[q2 * 4 + 2]); a[3] = (short)f2bf(xsv[q2 * 4 + 3]);
        *(s16x4*)&Xs[xn * 72 + d0 + q2 * 4] = a;
    }
    #pragma unroll
    for (int p = 0; p < 2; ++p) {
        const int g = tid + p * 256;
        const int c = g >> 3, slot = g & 7;
        *(s16x8*)&Wg[c * 72 + slot * 8] = *(const s16x8*)(WgT + (size_t)c * 64 + slot * 8);
    }
    __syncthreads();
    // phase 4: Y = Xs @ W_gcn, wave w owns rows w*16..w*16+15
    f32x4 yac[4] = {};
    #pragma unroll
    for (int ks = 0; ks < 2; ++ks) {
        const s16x8 xa = *(const s16x8*)&Xs[(w * 16 + lr) * 72 + ks * 32 + lk * 8];
        #pragma unroll
        for (int fc = 0; fc < 4; ++fc) {
            const s16x8 wb = *(const s16x8*)&Wg[(fc * 16 + lr) * 72 + ks * 32 + lk * 8];
            yac[fc] = __builtin_amdgcn_mfma_f32_16x16x32_bf16(xa, wb, yac[fc], 0, 0, 0);
        }
    }
    #pragma unroll
    for (int fc = 0; fc < 4; ++fc) {
        const int d = fc * 16 + lr;
        s16x4 o;
        o[0] = (short)f2bf(yac[fc][0]); o[1] = (short)f2bf(yac[fc][1]);
        o[2] = (short)f2bf(yac[fc][2]); o[3] = (short)f2bf(yac[fc][3]);
        *(s16x4*)(YT + ((size_t)bt * 64 + d) * N_NODE + n0 + w * 16 + lk * 4) = o;
    }
}

// ---------------------------------------------------------------------------
// K3: out[bt] = Gsum_eff @ Y[bt] + b_gcn.  MFMA, 128 rows x 2 bt per block.
// KS-way split-K over blockIdx.z; KS>1 uses atomicAdd onto zeroed output.
// ---------------------------------------------------------------------------
template <int KS>
__global__ __launch_bounds__(256) void k_prop(const unsigned short* __restrict__ Gsum,
                                              const unsigned short* __restrict__ YT,
                                              const float* __restrict__ b_gcn,
                                              float* __restrict__ out_base,
                                              long long bt_stride,
                                              float* __restrict__ p0_base) {
    __shared__ short Asm[128 * 32];
    __shared__ short Bsm[128 * 32];
    const int tid = threadIdx.x;
    const int m0 = blockIdx.x * 128;
    const int bt0 = blockIdx.y * 2;
    const int kz = blockIdx.z;
    const int kbeg = kz * (N_NODE / KS);
    const int kend = kbeg + (N_NODE / KS);
    const int lane = tid & 63;
    const int w = tid >> 6;
    const int wm = (w & 1) * 64;
    const int wn = (w >> 1) * 64;
    const int lr = lane & 15;
    const int lk = lane >> 4;
    const int srow = tid >> 2;
    const int sslot = tid & 3;
    const unsigned short* Yb0 = YT + (size_t)bt0 * 64 * N_NODE;
    const unsigned short* Yb1 = YT + (size_t)(bt0 + 1) * 64 * N_NODE;

    f32x4 acc[4][4] = {};
    s16x8 ra0, ra1, rb0, rb1;
    ra0 = *(const s16x8*)(Gsum + (size_t)(m0 + srow) * N_NODE + kbeg + sslot * 8);
    ra1 = *(const s16x8*)(Gsum + (size_t)(m0 + srow + 64) * N_NODE + kbeg + sslot * 8);
    rb0 = *(const s16x8*)(Yb0 + (size_t)srow * N_NODE + kbeg + sslot * 8);
    rb1 = *(const s16x8*)(Yb1 + (size_t)srow * N_NODE + kbeg + sslot * 8);

    for (int k0 = kbeg; k0 < kend; k0 += 32) {
        __syncthreads();
        *(s16x8*)&Asm[swz_off(srow, sslot)] = ra0;
        *(s16x8*)&Asm[swz_off(srow + 64, sslot)] = ra1;
        *(s16x8*)&Bsm[swz_off(srow, sslot)] = rb0;
        *(s16x8*)&Bsm[swz_off(srow + 64, sslot)] = rb1;
        __syncthreads();
        if (k0 + 32 < kend) {
            const int kn = k0 + 32;
            ra0 = *(const s16x8*)(Gsum + (size_t)(m0 + srow) * N_NODE + kn + sslot * 8);
            ra1 = *(const s16x8*)(Gsum + (size_t)(m0 + srow + 64) * N_NODE + kn + sslot * 8);
            rb0 = *(const s16x8*)(Yb0 + (size_t)srow * N_NODE + kn + sslot * 8);
            rb1 = *(const s16x8*)(Yb1 + (size_t)srow * N_NODE + kn + sslot * 8);
        }
        s16x8 af[4], bfr[4];
        #pragma unroll
        for (int fr = 0; fr < 4; ++fr)
            af[fr] = *(const s16x8*)&Asm[swz_off(wm + fr * 16 + lr, lk)];
        #pragma unroll
        for (int fc = 0; fc < 4; ++fc)
            bfr[fc] = *(const s16x8*)&Bsm[swz_off(wn + fc * 16 + lr, lk)];
        #pragma unroll
        for (int fr = 0; fr < 4; ++fr)
            #pragma unroll
            for (int fc = 0; fc < 4; ++fc)
                acc[fr][fc] = __builtin_amdgcn_mfma_f32_16x16x32_bf16(
                    af[fr], bfr[fc], acc[fr][fc], 0, 0, 0);
    }
    #pragma unroll
    for (int fc = 0; fc < 4; ++fc) {
        const int col = wn + fc * 16 + lr;
        const int btg = bt0 + (col >> 6);
        const int d = col & 63;
        const float bias = (KS == 1 || kz == 0) ? b_gcn[d] : 0.f;
        float* op = out_base + (size_t)btg * (size_t)bt_stride;
        float* pp = nullptr;
        if (KS == 1 && p0_base != nullptr && (btg % 10) == 9)
            pp = p0_base + (size_t)(btg / 10) * ((size_t)L_SEQ * ND);
        #pragma unroll
        for (int frr = 0; frr < 4; ++frr) {
            const int mb = m0 + wm + frr * 16 + lk * 4;
            #pragma unroll
            for (int reg = 0; reg < 4; ++reg) {
                const size_t off = (size_t)(mb + reg) * D_DIM + d;
                const float v = acc[frr][fc][reg] + bias;
                if (KS == 1) {
                    op[off] = v;
                    if (pp) pp[off] = v;
                } else {
                    atomicAdd(op + off, v);
                }
            }
        }
    }
}

// ---------------------------------------------------------------------------
// K4: forecast = P @ W_fore + b_fore (f32 VALU).
// ---------------------------------------------------------------------------
__global__ __launch_bounds__(256) void k_forecast(const float* __restrict__ P,
                                                  const float* __restrict__ W_fore,
                                                  const float* __restrict__ b_fore,
                                                  float* __restrict__ out) {
    __shared__ float Ast[64][64];
    const int tid = threadIdx.x;
    const size_t row0 = (size_t)blockIdx.x * 64;
    const int lrow = tid >> 4;
    const int lc4 = (tid & 15) * 4;
    const int r0 = (tid >> 4) * 4;
    const int c0 = (tid & 15) * 4;
    #pragma unroll
    for (int p = 0; p < 4; ++p) {
        const int r = lrow + p * 16;
        const float4 v = *(const float4*)(P + (row0 + r) * D_DIM + lc4);
        Ast[lc4 + 0][r] = v.x;
        Ast[lc4 + 1][r] = v.y;
        Ast[lc4 + 2][r] = v.z;
        Ast[lc4 + 3][r] = v.w;
    }
    __syncthreads();
    float acc[4][4][4];
    #pragma unroll
    for (int jc = 0; jc < 4; ++jc) {
        const float4 bb = *(const float4*)(b_fore + jc * 64 + c0);
        #pragma unroll
        for (int i = 0; i < 4; ++i) {
            acc[jc][i][0] = bb.x; acc[jc][i][1] = bb.y;
            acc[jc][i][2] = bb.z; acc[jc][i][3] = bb.w;
        }
    }
    #pragma unroll 4
    for (int k = 0; k < 64; ++k) {
        const float4 a4 = *(const float4*)&Ast[k][r0];
        const float a_[4] = {a4.x, a4.y, a4.z, a4.w};
        #pragma unroll
        for (int jc = 0; jc < 4; ++jc) {
            const float4 w4 = *(const float4*)(W_fore + (size_t)k * 256 + jc * 64 + c0);
            const float w_[4] = {w4.x, w4.y, w4.z, w4.w};
            #pragma unroll
            for (int i = 0; i < 4; ++i)
                #pragma unroll
                for (int j = 0; j < 4; ++j)
                    acc[jc][i][j] = fmaf(a_[i], w_[j], acc[jc][i][j]);
        }
    }
    #pragma unroll
    for (int i = 0; i < 4; ++i)
        #pragma unroll
        for (int jc = 0; jc < 4; ++jc) {
            float4 o;
            o.x = acc[jc][i][0]; o.y = acc[jc][i][1];
            o.z = acc[jc][i][2]; o.w = acc[jc][i][3];
            *(float4*)(out + (row0 + r0 + i) * 256 + jc * 64 + c0) = o;
        }
}

// ---------------------------------------------------------------------------
// K5: backcast = LN(X[:,2:] - relu(Z @ W_back + b_back)).
// ---------------------------------------------------------------------------
__global__ __launch_bounds__(256) void k_backcast(const float* __restrict__ Z,
                                                  const float* __restrict__ X,
                                                  const float* __restrict__ W_back,
                                                  const float* __restrict__ b_back,
                                                  const float* __restrict__ gamma,
                                                  const float* __restrict__ beta,
                                                  float* __restrict__ out) {
    const int tid = threadIdx.x;
    const int lane = tid & 63;
    const int wid = tid >> 6;
    const size_t row = (size_t)blockIdx.x * 4 + wid;
    const int bt = (int)(row >> 11);
    const int b = bt / 10;
    const int t = bt % 10;
    const size_t n = row & 2047;
    const float z = Z[row * D_DIM + lane];
    float back = b_back[lane];
    #pragma unroll 8
    for (int k = 0; k < 64; ++k) {
        const float zk = __shfl(z, k, 64);
        back = fmaf(zk, W_back[k * D_DIM + lane], back);
    }
    const float xr = X[(((size_t)b * L_SEQ + t + 2) * N_NODE + n) * D_DIM + lane];
    const float u = xr - fmaxf(back, 0.f);
    float s = u;
    #pragma unroll
    for (int off = 32; off > 0; off >>= 1) s += __shfl_xor(s, off, 64);
    const float mu = s * (1.f / 64.f);
    const float dv = u - mu;
    float s2 = dv * dv;
    #pragma unroll
    for (int off = 32; off > 0; off >>= 1) s2 += __shfl_xor(s2, off, 64);
    const float var = s2 * (1.f / 64.f);
    out[row * D_DIM + lane] = dv * rsqrtf(var + 1e-5f) * gamma[lane] + beta[lane];
}

// ---------------------------------------------------------------------------
extern "C" void kernel_launch(void* const* d_in, const int* in_sizes, int n_in,
                              void* d_out, int out_size, void* d_ws, size_t ws_size,
                              hipStream_t stream) {
    (void)in_sizes; (void)n_in; (void)out_size; (void)ws_size;
    const float* X      = (const float*)d_in[0];
    const float* X_spa  = (const float*)d_in[1];
    const float* G      = (const float*)d_in[2];
    const float* W_fc   = (const float*)d_in[3];
    const float* W_gcn  = (const float*)d_in[4];
    const float* b_gcn  = (const float*)d_in[5];
    const float* W_fore = (const float*)d_in[6];
    const float* b_fore = (const float*)d_in[7];
    const float* W_back = (const float*)d_in[8];
    const float* b_back = (const float*)d_in[9];
    const float* gamma  = (const float*)d_in[10];
    const float* beta   = (const float*)d_in[11];

    float* backcast = (float*)d_out;                      // 4*10*2048*64
    float* forecast = (float*)d_out + (size_t)5242880;    // 4*12*2048*256

    // workspace layout (80 MB), every byte written before read
    char* wsb = (char*)d_ws;
    unsigned short* Gsum = (unsigned short*)wsb;                        //  0.. 8 MB
    unsigned short* Ag   = (unsigned short*)(wsb + ((size_t)8 << 20));  //  8..16
    unsigned short* BTg  = (unsigned short*)(wsb + ((size_t)16 << 20)); // 16..24
    unsigned short* YTb  = (unsigned short*)(wsb + ((size_t)24 << 20)); // 24..34
    unsigned short* YTs  = (unsigned short*)(wsb + ((size_t)34 << 20)); // 34..35
    unsigned short* WfcT = (unsigned short*)(wsb + ((size_t)35 << 20)); // 72 KB
    unsigned short* WgT  = WfcT + 192 * 192;                            //  8 KB
    float* Z             = (float*)(wsb + ((size_t)36 << 20));          // 36..56
    float* P             = (float*)(wsb + ((size_t)56 << 20));          // 56..80

    const dim3 blk(256);

    // zero P frames 1..11 (targets of split-K atomics)
    hipMemsetAsync(P + ND, 0, (size_t)11 * ND * sizeof(float), stream);

    k_wprep<<<dim3(160), blk, 0, stream>>>(W_fc, W_gcn, WfcT, WgT);
    k_conv<<<dim3(32, 32), blk, 0, stream>>>(G, Ag, BTg);
    k_build<<<dim3(16, 16), blk, 0, stream>>>(Ag, BTg, G, Gsum);

    // Stage B: t=0..9 over 4 batches (40 bt)
    k_fc<<<dim3(32, 40), blk, 0, stream>>>(X_spa, X_spa + ND, X_spa + 2 * ND,
                                           WfcT, WgT, YTb, 10);
    k_prop<1><<<dim3(16, 20, 1), blk, 0, stream>>>(Gsum, YTb, b_gcn,
                                                   Z, (long long)ND, P);

    // Stage C: 11 serial autoregressive steps (4 bt each), split-K=4
    for (int i = 1; i <= 11; ++i) {
        const float *f0, *f1, *f2;
        if (i == 1)      { f0 = X_spa + 10 * ND; f1 = X_spa + 11 * ND; f2 = P; }
        else if (i == 2) { f0 = X_spa + 11 * ND; f1 = P;               f2 = P + ND; }
        else             { f0 = P + (size_t)(i - 3) * ND;
                           f1 = P + (size_t)(i - 2) * ND;
                           f2 = P + (size_t)(i - 1) * ND; }
        k_fc<<<dim3(32, 4), blk, 0, stream>>>(f0, f1, f2, WfcT, WgT, YTs, 1);
        k_prop<4><<<dim3(16, 2, 4), blk, 0, stream>>>(Gsum, YTs, b_gcn,
                                                      P + (size_t)i * ND,
                                                      (long long)(L_SEQ * ND),
                                                      nullptr);
    }

    k_forecast<<<dim3(1536), blk, 0, stream>>>(P, W_fore, b_fore, forecast);
    k_backcast<<<dim3(20480), blk, 0, stream>>>(Z, X, W_back, b_back,
                                                gamma, beta, backcast);
}